// Round 1
// baseline (183.132 us; speedup 1.0000x reference)
//
#include <hip/hip_runtime.h>
#include <hip/hip_bf16.h>

// SSIM loss, round 8: round-7 structure + DEEP software pipeline.
// Round 7 issued tile s+2's loads and consumed them in the SAME iteration
// (only one vblur of cover, full vmcnt drain every step -> latency-bound,
// all pipes <14% busy). Now: two pending raw-tile register buffers (A/B);
// each tile's loads are issued one full pair-iteration before consumption,
// and every hproc waits at vmcnt(4) (other buffer in flight), never 0,
// until the final tile. In-flight bytes/wave double and never drain.
// hblur: D[16 rows][16 cols] = A(raw) x B(const band W[k-n-3])
// vblur: D[16 cols][16 rows] = A(transposed h ring from LDS) x same B
// Per wave: private 16-col stripe x 128 out rows, no barriers in compute.

typedef float  f32x4  __attribute__((ext_vector_type(4)));
typedef short  short8 __attribute__((ext_vector_type(8)));
typedef short  short4v __attribute__((ext_vector_type(4)));
typedef float  float4v __attribute__((ext_vector_type(4)));

#define NBLOCK 1024   // x4 waves = 4096 waves; whole grid resident (4 blk/CU)

__device__ __forceinline__ short bf16s(float x) {
    __hip_bfloat16 h = __float2bfloat16(x);
    return __builtin_bit_cast(short, h);
}
__device__ __forceinline__ float bf16f(float x) {
    unsigned u = (unsigned)__builtin_bit_cast(unsigned short,
                                              __float2bfloat16(x)) << 16;
    return __builtin_bit_cast(float, u);
}

__global__ __launch_bounds__(256, 4)
void ssim_main(const float* __restrict__ pred, const float* __restrict__ targ,
               float* __restrict__ slotSum, unsigned int* __restrict__ grpCnt,
               unsigned int* __restrict__ finalCnt, float* __restrict__ out) {
    const float W[11] = {
        0.00102840f, 0.00759876f, 0.03600077f, 0.10936070f, 0.21300554f,
        0.26601173f,
        0.21300554f, 0.10936070f, 0.03600077f, 0.00759876f, 0.00102840f};

    __shared__ __align__(16) short hring[4][4][16][72];   // 36,864 B
    __shared__ float wsum[4];

    const int w     = threadIdx.x >> 6;
    const int L     = threadIdx.x & 63;
    const int n     = L & 15;
    const int quad  = L >> 4;
    const int waveId = blockIdx.x * 4 + w;
    const int img    = waveId >> 7;
    const int rem    = waveId & 127;
    const int q      = rem >> 5;
    const int stripe = rem & 31;
    const int c0     = stripe << 4;
    const int s0     = q << 3;
    const bool edge  = (stripe == 0) | (stripe == 31);

    const float* __restrict__ pim = pred + (size_t)img * 262144;
    const float* __restrict__ tim = targ + (size_t)img * 262144;

    float S = 0.f;
#pragma unroll
    for (int kk = 0; kk < 11; ++kk) S += bf16f(W[kk]);
    const float c2 = 1.0f / (S * S);

    short8 bw;
#pragma unroll
    for (int j = 0; j < 8; ++j) {
        const int d = quad * 8 + j - n - 3;
        bw[j] = bf16s((d >= 0 && d <= 10) ? W[d] : 0.f);
    }
    const f32x4 zc = {0.f, 0.f, 0.f, 0.f};

    float lsum = 0.f;
    float PA[8], TA[8], PB[8], TB[8];   // two pending raw tiles (pipeline)

    // ---- issue global loads for tile Tt into the given buffer ----
    auto hload = [&](int Tt, float (&P)[8], float (&T)[8]) {
        if ((unsigned)Tt > 31u) {
#pragma unroll
            for (int j = 0; j < 8; ++j) { P[j] = 0.f; T[j] = 0.f; }
            return;
        }
        const int r  = (Tt << 4) + n;
        const int cb = c0 - 8 + quad * 8;
        if (!edge) {
            const float4v* pp = (const float4v*)(pim + r * 512 + cb);
            const float4v* tp = (const float4v*)(tim + r * 512 + cb);
            const float4v p0 = pp[0], p1 = pp[1];
            const float4v t0 = tp[0], t1 = tp[1];
#pragma unroll
            for (int j = 0; j < 4; ++j) {
                P[j] = p0[j]; P[j + 4] = p1[j];
                T[j] = t0[j]; T[j + 4] = t1[j];
            }
        } else {
#pragma unroll
            for (int j = 0; j < 8; ++j) {
                const int col = cb + j;
                const int cc = min(max(col, 0), 511);
                const float pv = pim[r * 512 + cc];
                const float tv = tim[r * 512 + cc];
                const bool ok = (unsigned)col < 512u;
                P[j] = ok ? pv : 0.f;
                T[j] = ok ? tv : 0.f;
            }
        }
    };

    // ---- cvt + hblur MFMA + ring store for one pending tile ----
    auto hproc = [&](int Tt, float (&P)[8], float (&T)[8]) {
        const int wslot = (int)(((unsigned)(Tt << 4)) & 63u) + quad * 4;
        short4v o[4];
        if ((unsigned)Tt > 31u) {
#pragma unroll
            for (int f = 0; f < 4; ++f) o[f] = (short4v){0, 0, 0, 0};
        } else {
            short8 fa[4];
#pragma unroll
            for (int j = 0; j < 8; ++j) {
                const float u = P[j] + T[j], v = P[j] - T[j];
                fa[0][j] = bf16s(P[j]);
                fa[1][j] = bf16s(T[j]);
                fa[2][j] = bf16s(u * u);
                fa[3][j] = bf16s(v * v);
            }
#pragma unroll
            for (int f = 0; f < 4; ++f) {
                const f32x4 d = __builtin_amdgcn_mfma_f32_16x16x32_bf16(
                    fa[f], bw, zc, 0, 0, 0);
                short4v ov;
#pragma unroll
                for (int r2 = 0; r2 < 4; ++r2) ov[r2] = bf16s(d[r2]);
                o[f] = ov;
            }
        }
#pragma unroll
        for (int f = 0; f < 4; ++f)
            *(short4v*)&hring[w][f][n][wslot] = o[f];
    };

    // ---- vblur MFMA + SSIM math for output tile s ----
    auto vstep = [&](int s) {
        const int rslot0 = (int)(((unsigned)((s << 4) - 8)) & 63u);
        const int chunk  = (rslot0 + quad * 8) & 63;
        f32x4 dv[4];
#pragma unroll
        for (int f = 0; f < 4; ++f) {
            const short8 af = *(const short8*)&hring[w][f][n][chunk];
            dv[f] = __builtin_amdgcn_mfma_f32_16x16x32_bf16(af, bw, zc, 0, 0, 0);
        }
#pragma unroll
        for (int r = 0; r < 4; ++r) {
            const float m1 = dv[0][r] * c2, m2 = dv[1][r] * c2;
            const float Av = dv[2][r] * c2, Bv = dv[3][r] * c2;
            const float m12  = m1 * m2;
            const float smsq = m1 * m1 + m2 * m2;
            const float s12  = __builtin_fmaf(0.25f, Av - Bv, -m12);
            const float s1s2 = __builtin_fmaf(0.5f,  Av + Bv, -smsq);
            const float num = __builtin_fmaf(2.f, m12, 1e-4f) *
                              __builtin_fmaf(2.f, s12, 9e-4f);
            const float den = (smsq + 1e-4f) * (s1s2 + 9e-4f);
            float rc = __builtin_amdgcn_rcpf(den);
            rc = rc * (2.f - den * rc);
            lsum = __builtin_fmaf(num, rc, lsum);
        }
    };

    // ---- prologue: fill ring with s0-1..s0+1, leave B=s0+2, A=s0+3 pending
    hload(s0 - 1, PA, TA);
    hload(s0,     PB, TB);
    hproc(s0 - 1, PA, TA);          // waits vmcnt(4): B's loads in flight
    hload(s0 + 1, PA, TA);
    hproc(s0,     PB, TB);          // waits vmcnt(4)
    hload(s0 + 2, PB, TB);
    hproc(s0 + 1, PA, TA);          // waits vmcnt(4)
    hload(s0 + 3, PA, TA);

    // ---- 3 pair-steps: consume the tile loaded a full pair earlier ----
#pragma unroll
    for (int i = 0; i < 3; ++i) {
        const int s = s0 + 2 * i;
        vstep(s);
        hproc(s + 2, PB, TB);       // waits vmcnt(4): A=s+3 still in flight
        hload(s + 4, PB, TB);
        vstep(s + 1);
        hproc(s + 3, PA, TA);       // waits vmcnt(4): B=s+4 still in flight
        if (i < 2) hload(s + 5, PA, TA);
    }
    // ---- tail: procs up to s0+8 (last tile vblur(s0+7) needs) ----
    vstep(s0 + 6);
    hproc(s0 + 8, PB, TB);          // only vmcnt(0)-style wait in the loop
    vstep(s0 + 7);

    // ---- hierarchical reduce ----
#pragma unroll
    for (int off = 32; off > 0; off >>= 1)
        lsum += __shfl_down(lsum, off, 64);
    if (L == 0) wsum[w] = lsum;
    __syncthreads();
    if (threadIdx.x == 0) {
        const float bs = wsum[0] + wsum[1] + wsum[2] + wsum[3];
        const int g = blockIdx.x & 63;           // 64 groups x 16 blocks
        atomicAdd(&slotSum[g * 16], bs);         // slots 64 B apart
        __threadfence();
        if (atomicAdd(&grpCnt[g * 16], 1u) == 15u) {
            __threadfence();
            if (atomicAdd(finalCnt, 1u) == 63u) {
                float s = 0.f;
#pragma unroll
                for (int i = 0; i < 64; ++i)
                    s += atomicAdd(&slotSum[i * 16], 0.f);  // coherent reads
                out[0] = 1.0f - s * (1.0f / 8388608.0f);
            }
        }
    }
}

extern "C" void kernel_launch(void* const* d_in, const int* in_sizes, int n_in,
                              void* d_out, int out_size, void* d_ws,
                              size_t ws_size, hipStream_t stream) {
    const float* pred = (const float*)d_in[0];
    const float* targ = (const float*)d_in[1];
    // ws layout: [0,4096) slotSum[64] @64B stride; [4096,8192) grpCnt[64]
    //            @64B stride; [8192,8196) finalCnt
    float* slotSum = (float*)d_ws;
    unsigned int* grpCnt = (unsigned int*)((char*)d_ws + 4096);
    unsigned int* finalCnt = (unsigned int*)((char*)d_ws + 8192);

    hipMemsetAsync(d_ws, 0, 8196, stream);
    ssim_main<<<dim3(NBLOCK), dim3(256), 0, stream>>>(pred, targ, slotSum,
                                                      grpCnt, finalCnt,
                                                      (float*)d_out);
    (void)in_sizes; (void)n_in; (void)out_size; (void)ws_size;
}